// Round 1
// baseline (3920.145 us; speedup 1.0000x reference)
//
#include <hip/hip_runtime.h>
#include <math.h>

#define HH 320
#define WW 320
#define HW 102400
#define NB 8
#define NC 16
#define NITER 10
#define CGEPS 1e-10f

// ---------- complex helpers ----------
__device__ __forceinline__ float2 cmul(float2 a, float2 b) {
    return make_float2(a.x*b.x - a.y*b.y, a.x*b.y + a.y*b.x);
}
// a * conj(b)
__device__ __forceinline__ float2 cmulc(float2 a, float2 b) {
    return make_float2(a.x*b.x + a.y*b.y, a.y*b.x - a.x*b.y);
}
__device__ __forceinline__ float2 shflx(float2 v, int m) {
    return make_float2(__shfl_xor(v.x, m, 64), __shfl_xor(v.y, m, 64));
}

// ---------- twiddles ----------
struct Tw {
    float2 s[5];   // stage twiddles for h=32,16,8,4,2 : e^{-2pi i (t%h)/(2h)}
    float2 w5[4];  // W_320^{t*j}, j=1..4 : e^{-2pi i t j/320}
};

__device__ __forceinline__ void make_tw(int t, Tw& tw) {
#pragma unroll
    for (int s = 0; s < 5; ++s) {
        int h = 32 >> s;
        float ang = -3.14159265358979323846f / (float)h * (float)(t & (h - 1));
        float sv, cv; sincosf(ang, &sv, &cv);
        tw.s[s] = make_float2(cv, sv);
    }
#pragma unroll
    for (int j = 1; j <= 4; ++j) {
        float ang = -6.28318530717958647692f * (float)(t * j) / 320.0f;
        float sv, cv; sincosf(ang, &sv, &cv);
        tw.w5[j - 1] = make_float2(cv, sv);
    }
}

// ---------- radix-5 ----------
__device__ __forceinline__ void radix5(float2 a[5], bool inv) {
    const float C1 = 0.309016994374947424f, S1 = 0.951056516295153572f;
    const float C2 = -0.809016994374947424f, S2 = 0.587785252292473129f;
    float2 a0 = a[0];
    float2 t1 = make_float2(a[1].x + a[4].x, a[1].y + a[4].y);
    float2 t2 = make_float2(a[2].x + a[3].x, a[2].y + a[3].y);
    float2 t3 = make_float2(a[1].x - a[4].x, a[1].y - a[4].y);
    float2 t4 = make_float2(a[2].x - a[3].x, a[2].y - a[3].y);
    float2 u1 = make_float2(a0.x + C1*t1.x + C2*t2.x, a0.y + C1*t1.y + C2*t2.y);
    float2 u2 = make_float2(a0.x + C2*t1.x + C1*t2.x, a0.y + C2*t1.y + C1*t2.y);
    float2 v1 = make_float2(S1*t3.x + S2*t4.x, S1*t3.y + S2*t4.y);
    float2 v2 = make_float2(S2*t3.x - S1*t4.x, S2*t3.y - S1*t4.y);
    a[0] = make_float2(a0.x + t1.x + t2.x, a0.y + t1.y + t2.y);
    if (!inv) {
        a[1] = make_float2(u1.x + v1.y, u1.y - v1.x);
        a[4] = make_float2(u1.x - v1.y, u1.y + v1.x);
        a[2] = make_float2(u2.x + v2.y, u2.y - v2.x);
        a[3] = make_float2(u2.x - v2.y, u2.y + v2.x);
    } else {
        a[1] = make_float2(u1.x - v1.y, u1.y + v1.x);
        a[4] = make_float2(u1.x + v1.y, u1.y - v1.x);
        a[2] = make_float2(u2.x - v2.y, u2.y + v2.x);
        a[3] = make_float2(u2.x + v2.y, u2.y - v2.x);
    }
}

// ---------- length-64 FFT across the 64 lanes (radix-2 DIF / mirror DIT) ----------
__device__ __forceinline__ void lane_fft_fwd(float2& v, int t, const Tw& tw) {
#pragma unroll
    for (int s = 0; s < 6; ++s) {
        int h = 32 >> s;
        float2 o = shflx(v, h);
        if (t & h) {
            float2 d = make_float2(o.x - v.x, o.y - v.y);
            v = (s < 5) ? cmul(d, tw.s[s]) : d;
        } else {
            v = make_float2(v.x + o.x, v.y + o.y);
        }
    }
}
__device__ __forceinline__ void lane_fft_inv(float2& v, int t, const Tw& tw) {
#pragma unroll
    for (int s = 5; s >= 0; --s) {
        int h = 32 >> s;  // 1,2,4,8,16,32
        if ((t & h) && s < 5) v = cmulc(v, tw.s[s]);
        float2 o = shflx(v, h);
        if (t & h) v = make_float2(o.x - v.x, o.y - v.y);
        else       v = make_float2(v.x + o.x, v.y + o.y);
    }
}

// full forward: input a[k] = x[t+64k] (natural); output a[j] = X[5*rev6(t)+j]
__device__ __forceinline__ void fft320_fwd(float2 a[5], int t, const Tw& tw) {
    radix5(a, false);
#pragma unroll
    for (int j = 1; j < 5; ++j) a[j] = cmul(a[j], tw.w5[j - 1]);
#pragma unroll
    for (int j = 0; j < 5; ++j) lane_fft_fwd(a[j], t, tw);
}
// full inverse (unnormalized): input a[j] = X[5*rev6(t)+j]; output a[k] = 320*x[t+64k]
__device__ __forceinline__ void fft320_inv(float2 a[5], int t, const Tw& tw) {
#pragma unroll
    for (int j = 0; j < 5; ++j) lane_fft_inv(a[j], t, tw);
#pragma unroll
    for (int j = 1; j < 5; ++j) a[j] = cmulc(a[j], tw.w5[j - 1]);
    radix5(a, true);
}

// ---------- kernels ----------
__global__ void k_zero_scal(float* scal) { scal[threadIdx.x] = 0.0f; }

// maskpT[b][pw][ph] = mask[b][f(ph)][f(pw)] * 1/102400   (f(p) = 5*rev6(p/5) + p%5)
__global__ void k_maskp(const int* __restrict__ mask, float* __restrict__ maskpT) {
    int gid = blockIdx.x * 256 + threadIdx.x;
    int b = gid / HW; int rem = gid - b * HW;
    int pw = rem / WW; int ph = rem - pw * WW;
    int th = ph / 5, jh = ph - th * 5;
    int Kh = 5 * (int)(__brev((unsigned)th) >> 26) + jh;
    int tw_ = pw / 5, jw = pw - tw_ * 5;
    int Kw = 5 * (int)(__brev((unsigned)tw_) >> 26) + jw;
    float v = mask[(size_t)b * HW + Kh * WW + Kw] ? (1.0f / 102400.0f) : 0.0f;
    maskpT[gid] = v;
}

// x=0, r=p=rhs_c, rTr0 -> scal[b]
__global__ void k_init(const float* __restrict__ rhs, float2* __restrict__ x,
                       float2* __restrict__ r, float2* __restrict__ p,
                       float* __restrict__ scal) {
    int gid = blockIdx.x * 256 + threadIdx.x;
    int b = gid / HW; int hw = gid - b * HW;
    float re = rhs[(size_t)(b * 2) * HW + hw];
    float im = rhs[(size_t)(b * 2 + 1) * HW + hw];
    x[gid] = make_float2(0.f, 0.f);
    r[gid] = make_float2(re, im);
    p[gid] = make_float2(re, im);
    float d = re * re + im * im;
#pragma unroll
    for (int m = 32; m; m >>= 1) d += __shfl_xor(d, m, 64);
    if ((threadIdx.x & 63) == 0) atomicAdd(&scal[b], d);
}

// A: coil = csm*p, FFT along w, store digit-permuted rows
__global__ __launch_bounds__(256) void k_rowfft(const float* __restrict__ csm,
                                                const float2* __restrict__ p,
                                                float2* __restrict__ kbuf, int b0) {
    int row = blockIdx.x * 4 + (threadIdx.x >> 6);
    int t = threadIdx.x & 63;
    int h = row % HH; int bc = row / HH;
    int c = bc & 15; int bl = bc >> 4; int b = b0 + bl;
    Tw tw; make_tw(t, tw);
    const float2* csm2 = (const float2*)csm;
    size_t pbase = (size_t)b * HW + (size_t)h * WW;
    size_t cbase = ((size_t)(b * NC + c) * HH + h) * WW;
    float2 a[5];
#pragma unroll
    for (int k = 0; k < 5; ++k) {
        float2 pv = p[pbase + t + 64 * k];
        float2 cv = csm2[cbase + t + 64 * k];
        a[k] = cmul(cv, pv);
    }
    fft320_fwd(a, t, tw);
    size_t ob = ((size_t)bc * HH + h) * WW + 5 * t;
#pragma unroll
    for (int j = 0; j < 5; ++j) kbuf[ob + j] = a[j];
}

// B: per 320x8 column tile: FFT over h, mask, IFFT over h (in place)
__global__ __launch_bounds__(256) void k_colpass(float2* __restrict__ kbuf,
                                                 const float* __restrict__ maskpT, int b0) {
    int tile = blockIdx.x;
    int w0 = (tile % 40) * 8; int bc = tile / 40;
    int b = b0 + (bc >> 4);
    __shared__ float2 lds[HH * 9];
    size_t kbase = (size_t)bc * HW;
    for (int i = threadIdx.x; i < HH * 8; i += 256) {
        int hh = i >> 3, wc = i & 7;
        lds[hh * 9 + wc] = kbuf[kbase + (size_t)hh * WW + w0 + wc];
    }
    __syncthreads();
    int t = threadIdx.x & 63; int wv = threadIdx.x >> 6;
    Tw tw; make_tw(t, tw);
#pragma unroll
    for (int wc = 0; wc < 2; ++wc) {
        int w = wv * 2 + wc;
        float2 a[5];
#pragma unroll
        for (int k = 0; k < 5; ++k) a[k] = lds[(t + 64 * k) * 9 + w];
        fft320_fwd(a, t, tw);
        const float* mp = maskpT + ((size_t)b * WW + (w0 + w)) * HH + 5 * t;
#pragma unroll
        for (int j = 0; j < 5; ++j) { float m = mp[j]; a[j].x *= m; a[j].y *= m; }
        fft320_inv(a, t, tw);
#pragma unroll
        for (int k = 0; k < 5; ++k) lds[(t + 64 * k) * 9 + w] = a[k];
    }
    __syncthreads();
    for (int i = threadIdx.x; i < HH * 8; i += 256) {
        int hh = i >> 3, wc = i & 7;
        kbuf[kbase + (size_t)hh * WW + w0 + wc] = lds[hh * 9 + wc];
    }
}

// C: IFFT along w, combine conj(csm)*img over coils, Ap = . + lam*p, pAp reduction
__global__ __launch_bounds__(64) void k_combine(const float* __restrict__ csm,
                                                const float2* __restrict__ kbuf,
                                                const float2* __restrict__ p,
                                                float2* __restrict__ Ap,
                                                const float* __restrict__ lam,
                                                float* __restrict__ scal, int b0, int it) {
    int t = threadIdx.x;
    int h = blockIdx.x % HH; int bl = blockIdx.x / HH; int b = b0 + bl;
    Tw tw; make_tw(t, tw);
    const float2* csm2 = (const float2*)csm;
    float2 acc[5];
#pragma unroll
    for (int k = 0; k < 5; ++k) acc[k] = make_float2(0.f, 0.f);
    for (int c = 0; c < NC; ++c) {
        size_t kb = ((size_t)(bl * NC + c) * HH + h) * WW + 5 * t;
        float2 a[5];
#pragma unroll
        for (int j = 0; j < 5; ++j) a[j] = kbuf[kb + j];
        fft320_inv(a, t, tw);
        size_t cb = ((size_t)(b * NC + c) * HH + h) * WW;
#pragma unroll
        for (int k = 0; k < 5; ++k) {
            float2 cv = csm2[cb + t + 64 * k];
            float2 m = cmulc(a[k], cv);  // img * conj(csm)
            acc[k].x += m.x; acc[k].y += m.y;
        }
    }
    float lamv = lam[0];
    size_t pb = (size_t)b * HW + (size_t)h * WW;
    float dot = 0.f;
#pragma unroll
    for (int k = 0; k < 5; ++k) {
        float2 pv = p[pb + t + 64 * k];
        float2 apv = make_float2(acc[k].x + lamv * pv.x, acc[k].y + lamv * pv.y);
        Ap[pb + t + 64 * k] = apv;
        dot += pv.x * apv.x + pv.y * apv.y;
    }
#pragma unroll
    for (int m = 32; m; m >>= 1) dot += __shfl_xor(dot, m, 64);
    if (t == 0) atomicAdd(&scal[8 + it * 8 + b], dot);
}

// U1: x += a p; r -= a Ap; rTr_new reduction
__global__ void k_update1(float2* __restrict__ x, float2* __restrict__ r,
                          const float2* __restrict__ p, const float2* __restrict__ Ap,
                          float* __restrict__ scal, int it) {
    if (((const int*)scal)[168] != 0) return;
    int gid = blockIdx.x * 256 + threadIdx.x;
    int b = gid / HW;
    float alpha = scal[b] / scal[8 + it * 8 + b];
    float2 pv = p[gid], apv = Ap[gid];
    float2 xv = x[gid];
    x[gid] = make_float2(xv.x + alpha * pv.x, xv.y + alpha * pv.y);
    float2 rv = r[gid];
    float2 rn = make_float2(rv.x - alpha * apv.x, rv.y - alpha * apv.y);
    r[gid] = rn;
    float d = rn.x * rn.x + rn.y * rn.y;
#pragma unroll
    for (int m = 32; m; m >>= 1) d += __shfl_xor(d, m, 64);
    if ((threadIdx.x & 63) == 0) atomicAdd(&scal[88 + it * 8 + b], d);
}

// U2: p = r + beta p
__global__ void k_update2(const float2* __restrict__ r, float2* __restrict__ p,
                          const float* __restrict__ scal, int it) {
    if (((const int*)scal)[168] != 0) return;
    int gid = blockIdx.x * 256 + threadIdx.x;
    int b = gid / HW;
    float beta = scal[88 + it * 8 + b] / scal[b];
    float2 rv = r[gid], pv = p[gid];
    p[gid] = make_float2(rv.x + beta * pv.x, rv.y + beta * pv.y);
}

// U3: rTrc <- rTr_new; done |= max(rTr_new) < EPS
__global__ void k_update3(float* __restrict__ scal, int it) {
    int t = threadIdx.x;
    int* dn = (int*)scal + 168;
    if (*dn) return;
    float v = (t < 8) ? scal[88 + it * 8 + t] : 0.0f;
    if (t < 8) scal[t] = v;
    float m = v;
#pragma unroll
    for (int mk = 32; mk; mk >>= 1) m = fmaxf(m, __shfl_xor(m, mk, 64));
    if (t == 0 && m < CGEPS) *dn = 1;
}

extern "C" void kernel_launch(void* const* d_in, const int* in_sizes, int n_in,
                              void* d_out, int out_size, void* d_ws, size_t ws_size,
                              hipStream_t stream) {
    const float* rhs = (const float*)d_in[0];
    const float* csm = (const float*)d_in[1];
    const int* mask = (const int*)d_in[2];
    const float* lam = (const float*)d_in[3];

    char* w = (char*)d_ws;
    float2* x = (float2*)w;        w += (size_t)NB * HW * sizeof(float2);
    float2* r = (float2*)w;        w += (size_t)NB * HW * sizeof(float2);
    float2* p = (float2*)w;        w += (size_t)NB * HW * sizeof(float2);
    float2* Ap = (float2*)w;       w += (size_t)NB * HW * sizeof(float2);
    float* maskpT = (float*)w;     w += (size_t)NB * HW * sizeof(float);
    float* scal = (float*)w;       w += 4096;
    float2* kbuf = (float2*)w;

    size_t used = (size_t)(w - (char*)d_ws);
    size_t per_b = (size_t)NC * HW * sizeof(float2);  // 13.1 MB per batch
    int CB = 1;
    if (ws_size > used) {
        size_t avail = ws_size - used;
        CB = (int)(avail / per_b);
        if (CB > NB) CB = NB;
        if (CB < 1) CB = 1;
    }

    k_zero_scal<<<1, 256, 0, stream>>>(scal);
    k_maskp<<<(NB * HW) / 256, 256, 0, stream>>>(mask, maskpT);
    k_init<<<(NB * HW) / 256, 256, 0, stream>>>(rhs, x, r, p, scal);

    for (int it = 0; it < NITER; ++it) {
        for (int b0 = 0; b0 < NB; b0 += CB) {
            int nb = (NB - b0 < CB) ? (NB - b0) : CB;
            k_rowfft<<<nb * NC * HH / 4, 256, 0, stream>>>(csm, p, kbuf, b0);
            k_colpass<<<nb * NC * 40, 256, 0, stream>>>(kbuf, maskpT, b0);
            k_combine<<<nb * HH, 64, 0, stream>>>(csm, kbuf, p, Ap, lam, scal, b0, it);
        }
        k_update1<<<(NB * HW) / 256, 256, 0, stream>>>(x, r, p, Ap, scal, it);
        k_update2<<<(NB * HW) / 256, 256, 0, stream>>>(r, p, scal, it);
        k_update3<<<1, 64, 0, stream>>>(scal, it);
    }
    hipMemcpyAsync(d_out, x, (size_t)NB * HW * sizeof(float2),
                   hipMemcpyDeviceToDevice, stream);
}

// Round 2
// 2231.983 us; speedup vs baseline: 1.7564x; 1.7564x over previous
//
#include <hip/hip_runtime.h>
#include <math.h>

#define HH 320
#define WW 320
#define HW 102400
#define NB 8
#define NC 16
#define NITER 10
#define CGEPS 1e-10f

// ---------- complex helpers ----------
__device__ __forceinline__ float2 cmul(float2 a, float2 b) {
    return make_float2(a.x*b.x - a.y*b.y, a.x*b.y + a.y*b.x);
}
// a * conj(b)
__device__ __forceinline__ float2 cmulc(float2 a, float2 b) {
    return make_float2(a.x*b.x + a.y*b.y, a.y*b.x - a.x*b.y);
}
__device__ __forceinline__ float2 shflx(float2 v, int m) {
    return make_float2(__shfl_xor(v.x, m, 64), __shfl_xor(v.y, m, 64));
}

// ---------- twiddles ----------
struct Tw {
    float2 s[5];   // stage twiddles for h=32,16,8,4,2 : e^{-2pi i (t%h)/(2h)}
    float2 w5[4];  // W_320^{t*j}, j=1..4 : e^{-2pi i t j/320}
};

__device__ __forceinline__ void make_tw(int t, Tw& tw) {
#pragma unroll
    for (int s = 0; s < 5; ++s) {
        int h = 32 >> s;
        float ang = -3.14159265358979323846f / (float)h * (float)(t & (h - 1));
        float sv, cv; sincosf(ang, &sv, &cv);
        tw.s[s] = make_float2(cv, sv);
    }
#pragma unroll
    for (int j = 1; j <= 4; ++j) {
        float ang = -6.28318530717958647692f * (float)(t * j) / 320.0f;
        float sv, cv; sincosf(ang, &sv, &cv);
        tw.w5[j - 1] = make_float2(cv, sv);
    }
}

// ---------- radix-5 ----------
__device__ __forceinline__ void radix5(float2 a[5], bool inv) {
    const float C1 = 0.309016994374947424f, S1 = 0.951056516295153572f;
    const float C2 = -0.809016994374947424f, S2 = 0.587785252292473129f;
    float2 a0 = a[0];
    float2 t1 = make_float2(a[1].x + a[4].x, a[1].y + a[4].y);
    float2 t2 = make_float2(a[2].x + a[3].x, a[2].y + a[3].y);
    float2 t3 = make_float2(a[1].x - a[4].x, a[1].y - a[4].y);
    float2 t4 = make_float2(a[2].x - a[3].x, a[2].y - a[3].y);
    float2 u1 = make_float2(a0.x + C1*t1.x + C2*t2.x, a0.y + C1*t1.y + C2*t2.y);
    float2 u2 = make_float2(a0.x + C2*t1.x + C1*t2.x, a0.y + C2*t1.y + C1*t2.y);
    float2 v1 = make_float2(S1*t3.x + S2*t4.x, S1*t3.y + S2*t4.y);
    float2 v2 = make_float2(S2*t3.x - S1*t4.x, S2*t3.y - S1*t4.y);
    a[0] = make_float2(a0.x + t1.x + t2.x, a0.y + t1.y + t2.y);
    if (!inv) {
        a[1] = make_float2(u1.x + v1.y, u1.y - v1.x);
        a[4] = make_float2(u1.x - v1.y, u1.y + v1.x);
        a[2] = make_float2(u2.x + v2.y, u2.y - v2.x);
        a[3] = make_float2(u2.x - v2.y, u2.y + v2.x);
    } else {
        a[1] = make_float2(u1.x - v1.y, u1.y + v1.x);
        a[4] = make_float2(u1.x + v1.y, u1.y - v1.x);
        a[2] = make_float2(u2.x - v2.y, u2.y + v2.x);
        a[3] = make_float2(u2.x + v2.y, u2.y - v2.x);
    }
}

// ---------- length-64 FFT across the 64 lanes (radix-2 DIF / mirror DIT) ----------
__device__ __forceinline__ void lane_fft_fwd(float2& v, int t, const Tw& tw) {
#pragma unroll
    for (int s = 0; s < 6; ++s) {
        int h = 32 >> s;
        float2 o = shflx(v, h);
        if (t & h) {
            float2 d = make_float2(o.x - v.x, o.y - v.y);
            v = (s < 5) ? cmul(d, tw.s[s]) : d;
        } else {
            v = make_float2(v.x + o.x, v.y + o.y);
        }
    }
}
__device__ __forceinline__ void lane_fft_inv(float2& v, int t, const Tw& tw) {
#pragma unroll
    for (int s = 5; s >= 0; --s) {
        int h = 32 >> s;  // 1,2,4,8,16,32
        if ((t & h) && s < 5) v = cmulc(v, tw.s[s]);
        float2 o = shflx(v, h);
        if (t & h) v = make_float2(o.x - v.x, o.y - v.y);
        else       v = make_float2(v.x + o.x, v.y + o.y);
    }
}

// full forward: input a[k] = x[t+64k] (natural); output a[j] = X[5*rev6(t)+j]
__device__ __forceinline__ void fft320_fwd(float2 a[5], int t, const Tw& tw) {
    radix5(a, false);
#pragma unroll
    for (int j = 1; j < 5; ++j) a[j] = cmul(a[j], tw.w5[j - 1]);
#pragma unroll
    for (int j = 0; j < 5; ++j) lane_fft_fwd(a[j], t, tw);
}
// full inverse (unnormalized): input a[j] = X[5*rev6(t)+j]; output a[k] = 320*x[t+64k]
__device__ __forceinline__ void fft320_inv(float2 a[5], int t, const Tw& tw) {
#pragma unroll
    for (int j = 0; j < 5; ++j) lane_fft_inv(a[j], t, tw);
#pragma unroll
    for (int j = 1; j < 5; ++j) a[j] = cmulc(a[j], tw.w5[j - 1]);
    radix5(a, true);
}

// ---------- block reduction: wave shuffle + LDS + single atomic ----------
__device__ __forceinline__ void block_reduce_atomic(float d, float* dst) {
#pragma unroll
    for (int m = 32; m; m >>= 1) d += __shfl_xor(d, m, 64);
    __shared__ float ls[4];
    int lane = threadIdx.x & 63, wv = threadIdx.x >> 6;
    if (lane == 0) ls[wv] = d;
    __syncthreads();
    if (threadIdx.x == 0) atomicAdd(dst, ls[0] + ls[1] + ls[2] + ls[3]);
}

// ---------- kernels ----------
__global__ void k_zero_scal(float* scal) { scal[threadIdx.x] = 0.0f; }

// maskpT[b][pw][ph] = mask[b][f(ph)][f(pw)] * 1/102400   (f(p) = 5*rev6(p/5) + p%5)
__global__ void k_maskp(const int* __restrict__ mask, float* __restrict__ maskpT) {
    int gid = blockIdx.x * 256 + threadIdx.x;
    int b = gid / HW; int rem = gid - b * HW;
    int pw = rem / WW; int ph = rem - pw * WW;
    int th = ph / 5, jh = ph - th * 5;
    int Kh = 5 * (int)(__brev((unsigned)th) >> 26) + jh;
    int tw_ = pw / 5, jw = pw - tw_ * 5;
    int Kw = 5 * (int)(__brev((unsigned)tw_) >> 26) + jw;
    float v = mask[(size_t)b * HW + Kh * WW + Kw] ? (1.0f / 102400.0f) : 0.0f;
    maskpT[gid] = v;
}

// x=0, r=p=rhs_c, rTr0 -> scal[b].  400 blocks, 8 complex/thread, float4 I/O.
__global__ __launch_bounds__(256) void k_init(const float* __restrict__ rhs,
                                              float4* __restrict__ x4,
                                              float4* __restrict__ r4,
                                              float4* __restrict__ p4,
                                              float* __restrict__ scal) {
    int blk = blockIdx.x, tid = threadIdx.x;
    int b = blk / 50;                            // 50 blocks per batch
    size_t off = (size_t)blk * 2048 + (size_t)tid * 8;   // complex index
    size_t hw = off - (size_t)b * HW;
    const float4* re4 = (const float4*)(rhs + (size_t)(2 * b) * HW + hw);
    const float4* im4 = (const float4*)(rhs + (size_t)(2 * b + 1) * HW + hw);
    float4 re0 = re4[0], re1 = re4[1];
    float4 im0 = im4[0], im1 = im4[1];
    float4 z = make_float4(0.f, 0.f, 0.f, 0.f);
    size_t o4 = off >> 1;                        // float4 index (2 complex each)
    x4[o4 + 0] = z; x4[o4 + 1] = z; x4[o4 + 2] = z; x4[o4 + 3] = z;
    float4 v0 = make_float4(re0.x, im0.x, re0.y, im0.y);
    float4 v1 = make_float4(re0.z, im0.z, re0.w, im0.w);
    float4 v2 = make_float4(re1.x, im1.x, re1.y, im1.y);
    float4 v3 = make_float4(re1.z, im1.z, re1.w, im1.w);
    r4[o4 + 0] = v0; r4[o4 + 1] = v1; r4[o4 + 2] = v2; r4[o4 + 3] = v3;
    p4[o4 + 0] = v0; p4[o4 + 1] = v1; p4[o4 + 2] = v2; p4[o4 + 3] = v3;
    float d = re0.x*re0.x + re0.y*re0.y + re0.z*re0.z + re0.w*re0.w
            + re1.x*re1.x + re1.y*re1.y + re1.z*re1.z + re1.w*re1.w
            + im0.x*im0.x + im0.y*im0.y + im0.z*im0.z + im0.w*im0.w
            + im1.x*im1.x + im1.y*im1.y + im1.z*im1.z + im1.w*im1.w;
    block_reduce_atomic(d, &scal[b]);
}

// A: coil = csm*p, FFT along w, store digit-permuted rows
__global__ __launch_bounds__(256) void k_rowfft(const float* __restrict__ csm,
                                                const float2* __restrict__ p,
                                                float2* __restrict__ kbuf, int b0) {
    int row = blockIdx.x * 4 + (threadIdx.x >> 6);
    int t = threadIdx.x & 63;
    int h = row % HH; int bc = row / HH;
    int c = bc & 15; int bl = bc >> 4; int b = b0 + bl;
    Tw tw; make_tw(t, tw);
    const float2* csm2 = (const float2*)csm;
    size_t pbase = (size_t)b * HW + (size_t)h * WW;
    size_t cbase = ((size_t)(b * NC + c) * HH + h) * WW;
    float2 a[5];
#pragma unroll
    for (int k = 0; k < 5; ++k) {
        float2 pv = p[pbase + t + 64 * k];
        float2 cv = csm2[cbase + t + 64 * k];
        a[k] = cmul(cv, pv);
    }
    fft320_fwd(a, t, tw);
    size_t ob = ((size_t)bc * HH + h) * WW + 5 * t;
#pragma unroll
    for (int j = 0; j < 5; ++j) kbuf[ob + j] = a[j];
}

// B: per 320x8 column tile: FFT over h, mask, IFFT over h (in place)
__global__ __launch_bounds__(256) void k_colpass(float2* __restrict__ kbuf,
                                                 const float* __restrict__ maskpT, int b0) {
    int tile = blockIdx.x;
    int w0 = (tile % 40) * 8; int bc = tile / 40;
    int b = b0 + (bc >> 4);
    __shared__ float2 lds[HH * 9];
    size_t kbase = (size_t)bc * HW;
    for (int i = threadIdx.x; i < HH * 8; i += 256) {
        int hh = i >> 3, wc = i & 7;
        lds[hh * 9 + wc] = kbuf[kbase + (size_t)hh * WW + w0 + wc];
    }
    __syncthreads();
    int t = threadIdx.x & 63; int wv = threadIdx.x >> 6;
    Tw tw; make_tw(t, tw);
#pragma unroll
    for (int wc = 0; wc < 2; ++wc) {
        int w = wv * 2 + wc;
        float2 a[5];
#pragma unroll
        for (int k = 0; k < 5; ++k) a[k] = lds[(t + 64 * k) * 9 + w];
        fft320_fwd(a, t, tw);
        const float* mp = maskpT + ((size_t)b * WW + (w0 + w)) * HH + 5 * t;
#pragma unroll
        for (int j = 0; j < 5; ++j) { float m = mp[j]; a[j].x *= m; a[j].y *= m; }
        fft320_inv(a, t, tw);
#pragma unroll
        for (int k = 0; k < 5; ++k) lds[(t + 64 * k) * 9 + w] = a[k];
    }
    __syncthreads();
    for (int i = threadIdx.x; i < HH * 8; i += 256) {
        int hh = i >> 3, wc = i & 7;
        kbuf[kbase + (size_t)hh * WW + w0 + wc] = lds[hh * 9 + wc];
    }
}

// C: IFFT along w, combine conj(csm)*img over coils, Ap = . + lam*p, pAp reduction
__global__ __launch_bounds__(64) void k_combine(const float* __restrict__ csm,
                                                const float2* __restrict__ kbuf,
                                                const float2* __restrict__ p,
                                                float2* __restrict__ Ap,
                                                const float* __restrict__ lam,
                                                float* __restrict__ scal, int b0, int it) {
    int t = threadIdx.x;
    int h = blockIdx.x % HH; int bl = blockIdx.x / HH; int b = b0 + bl;
    Tw tw; make_tw(t, tw);
    const float2* csm2 = (const float2*)csm;
    float2 acc[5];
#pragma unroll
    for (int k = 0; k < 5; ++k) acc[k] = make_float2(0.f, 0.f);
    for (int c = 0; c < NC; ++c) {
        size_t kb = ((size_t)(bl * NC + c) * HH + h) * WW + 5 * t;
        float2 a[5];
#pragma unroll
        for (int j = 0; j < 5; ++j) a[j] = kbuf[kb + j];
        fft320_inv(a, t, tw);
        size_t cb = ((size_t)(b * NC + c) * HH + h) * WW;
#pragma unroll
        for (int k = 0; k < 5; ++k) {
            float2 cv = csm2[cb + t + 64 * k];
            float2 m = cmulc(a[k], cv);  // img * conj(csm)
            acc[k].x += m.x; acc[k].y += m.y;
        }
    }
    float lamv = lam[0];
    size_t pb = (size_t)b * HW + (size_t)h * WW;
    float dot = 0.f;
#pragma unroll
    for (int k = 0; k < 5; ++k) {
        float2 pv = p[pb + t + 64 * k];
        float2 apv = make_float2(acc[k].x + lamv * pv.x, acc[k].y + lamv * pv.y);
        Ap[pb + t + 64 * k] = apv;
        dot += pv.x * apv.x + pv.y * apv.y;
    }
#pragma unroll
    for (int m = 32; m; m >>= 1) dot += __shfl_xor(dot, m, 64);
    if (t == 0) atomicAdd(&scal[8 + it * 8 + b], dot);
}

// U1: x += a p; r -= a Ap; rTr_new reduction.  400 blocks, 8 complex/thread.
__global__ __launch_bounds__(256) void k_update1(float4* __restrict__ x,
                                                 float4* __restrict__ r,
                                                 const float4* __restrict__ p,
                                                 const float4* __restrict__ Ap,
                                                 float* __restrict__ scal, int it) {
    if (((const int*)scal)[168] != 0) return;
    int blk = blockIdx.x, tid = threadIdx.x;
    int b = blk / 50;
    float alpha = scal[b] / scal[8 + it * 8 + b];
    size_t o4 = (size_t)blk * 1024 + (size_t)tid * 4;  // float4 units
    float d = 0.f;
#pragma unroll
    for (int j = 0; j < 4; ++j) {
        float4 pv = p[o4 + j], av = Ap[o4 + j];
        float4 xv = x[o4 + j], rv = r[o4 + j];
        xv.x += alpha * pv.x; xv.y += alpha * pv.y;
        xv.z += alpha * pv.z; xv.w += alpha * pv.w;
        rv.x -= alpha * av.x; rv.y -= alpha * av.y;
        rv.z -= alpha * av.z; rv.w -= alpha * av.w;
        x[o4 + j] = xv; r[o4 + j] = rv;
        d += rv.x*rv.x + rv.y*rv.y + rv.z*rv.z + rv.w*rv.w;
    }
    block_reduce_atomic(d, &scal[88 + it * 8 + b]);
}

// U2: p = r + beta p.  400 blocks, 8 complex/thread.
__global__ __launch_bounds__(256) void k_update2(const float4* __restrict__ r,
                                                 float4* __restrict__ p,
                                                 const float* __restrict__ scal, int it) {
    if (((const int*)scal)[168] != 0) return;
    int blk = blockIdx.x, tid = threadIdx.x;
    int b = blk / 50;
    float beta = scal[88 + it * 8 + b] / scal[b];
    size_t o4 = (size_t)blk * 1024 + (size_t)tid * 4;
#pragma unroll
    for (int j = 0; j < 4; ++j) {
        float4 rv = r[o4 + j], pv = p[o4 + j];
        pv.x = rv.x + beta * pv.x; pv.y = rv.y + beta * pv.y;
        pv.z = rv.z + beta * pv.z; pv.w = rv.w + beta * pv.w;
        p[o4 + j] = pv;
    }
}

// U3: rTrc <- rTr_new; done |= max(rTr_new) < EPS
__global__ void k_update3(float* __restrict__ scal, int it) {
    int t = threadIdx.x;
    int* dn = (int*)scal + 168;
    if (*dn) return;
    float v = (t < 8) ? scal[88 + it * 8 + t] : 0.0f;
    if (t < 8) scal[t] = v;
    float m = v;
#pragma unroll
    for (int mk = 32; mk; mk >>= 1) m = fmaxf(m, __shfl_xor(m, mk, 64));
    if (t == 0 && m < CGEPS) *dn = 1;
}

extern "C" void kernel_launch(void* const* d_in, const int* in_sizes, int n_in,
                              void* d_out, int out_size, void* d_ws, size_t ws_size,
                              hipStream_t stream) {
    const float* rhs = (const float*)d_in[0];
    const float* csm = (const float*)d_in[1];
    const int* mask = (const int*)d_in[2];
    const float* lam = (const float*)d_in[3];

    char* w = (char*)d_ws;
    float2* x = (float2*)w;        w += (size_t)NB * HW * sizeof(float2);
    float2* r = (float2*)w;        w += (size_t)NB * HW * sizeof(float2);
    float2* p = (float2*)w;        w += (size_t)NB * HW * sizeof(float2);
    float2* Ap = (float2*)w;       w += (size_t)NB * HW * sizeof(float2);
    float* maskpT = (float*)w;     w += (size_t)NB * HW * sizeof(float);
    float* scal = (float*)w;       w += 4096;
    float2* kbuf = (float2*)w;

    size_t used = (size_t)(w - (char*)d_ws);
    size_t per_b = (size_t)NC * HW * sizeof(float2);  // 13.1 MB per batch
    int CB = 1;
    if (ws_size > used) {
        size_t avail = ws_size - used;
        CB = (int)(avail / per_b);
        if (CB > NB) CB = NB;
        if (CB < 1) CB = 1;
    }

    k_zero_scal<<<1, 256, 0, stream>>>(scal);
    k_maskp<<<(NB * HW) / 256, 256, 0, stream>>>(mask, maskpT);
    k_init<<<400, 256, 0, stream>>>(rhs, (float4*)x, (float4*)r, (float4*)p, scal);

    for (int it = 0; it < NITER; ++it) {
        for (int b0 = 0; b0 < NB; b0 += CB) {
            int nb = (NB - b0 < CB) ? (NB - b0) : CB;
            k_rowfft<<<nb * NC * HH / 4, 256, 0, stream>>>(csm, p, kbuf, b0);
            k_colpass<<<nb * NC * 40, 256, 0, stream>>>(kbuf, maskpT, b0);
            k_combine<<<nb * HH, 64, 0, stream>>>(csm, kbuf, p, Ap, lam, scal, b0, it);
        }
        k_update1<<<400, 256, 0, stream>>>((float4*)x, (float4*)r, (const float4*)p,
                                           (const float4*)Ap, scal, it);
        k_update2<<<400, 256, 0, stream>>>((const float4*)r, (float4*)p, scal, it);
        k_update3<<<1, 64, 0, stream>>>(scal, it);
    }
    hipMemcpyAsync(d_out, x, (size_t)NB * HW * sizeof(float2),
                   hipMemcpyDeviceToDevice, stream);
}

// Round 8
// 2178.197 us; speedup vs baseline: 1.7997x; 1.0247x over previous
//
#include <hip/hip_runtime.h>
#include <math.h>

#define HH 320
#define WW 320
#define HW 102400
#define NB 8
#define NC 16
#define NITER 10
#define CGEPS 1e-10f

// ---------- complex helpers ----------
__device__ __forceinline__ float2 cmul(float2 a, float2 b) {
    return make_float2(a.x*b.x - a.y*b.y, a.x*b.y + a.y*b.x);
}
// a * conj(b)
__device__ __forceinline__ float2 cmulc(float2 a, float2 b) {
    return make_float2(a.x*b.x + a.y*b.y, a.y*b.x - a.x*b.y);
}
__device__ __forceinline__ float2 shflx(float2 v, int m) {
    return make_float2(__shfl_xor(v.x, m, 64), __shfl_xor(v.y, m, 64));
}

// ---------- branchless per-lane twiddle state ----------
// fwd stage s (h=32>>s): o=shfl_xor(v,h); v=(t&h)? cmul(o-v,tw_s): v+o
//   == cmul(o + sgn[s]*v, f[s])  with f[s]=(t&h)?tw_s:(1,0), sgn=(t&h)?-1:+1
// inv stage s: pre-mult by i[s]=(t&h)?conj(tw_s):(1,0), then o+sgn[s]*v.
struct TwF { float2 f[5]; float sgn[6]; float2 w5[4]; };
struct TwI { float2 i[5]; float sgn[6]; float2 w5[4]; };

__device__ __forceinline__ void make_sgn_w5(int t, float* sgn, float2* w5) {
#pragma unroll
    for (int s = 0; s < 6; ++s) sgn[s] = (t & (32 >> s)) ? -1.0f : 1.0f;
#pragma unroll
    for (int j = 1; j <= 4; ++j) {
        float ang = -6.28318530717958647692f * (float)(t * j) / 320.0f;
        float sv, cv; sincosf(ang, &sv, &cv);
        w5[j - 1] = make_float2(cv, sv);
    }
}
__device__ __forceinline__ void make_twf(int t, TwF& m) {
    make_sgn_w5(t, m.sgn, m.w5);
#pragma unroll
    for (int s = 0; s < 5; ++s) {
        int h = 32 >> s;
        float ang = -3.14159265358979323846f / (float)h * (float)(t & (h - 1));
        float sv, cv; sincosf(ang, &sv, &cv);
        bool msk = (t & h) != 0;
        m.f[s] = msk ? make_float2(cv, sv) : make_float2(1.f, 0.f);
    }
}
__device__ __forceinline__ void make_twi(int t, TwI& m) {
    make_sgn_w5(t, m.sgn, m.w5);
#pragma unroll
    for (int s = 0; s < 5; ++s) {
        int h = 32 >> s;
        float ang = -3.14159265358979323846f / (float)h * (float)(t & (h - 1));
        float sv, cv; sincosf(ang, &sv, &cv);
        bool msk = (t & h) != 0;
        m.i[s] = msk ? make_float2(cv, -sv) : make_float2(1.f, 0.f);  // conj
    }
}

// ---------- radix-5 ----------
__device__ __forceinline__ void radix5(float2 a[5], bool inv) {
    const float C1 = 0.309016994374947424f, S1 = 0.951056516295153572f;
    const float C2 = -0.809016994374947424f, S2 = 0.587785252292473129f;
    float2 a0 = a[0];
    float2 t1 = make_float2(a[1].x + a[4].x, a[1].y + a[4].y);
    float2 t2 = make_float2(a[2].x + a[3].x, a[2].y + a[3].y);
    float2 t3 = make_float2(a[1].x - a[4].x, a[1].y - a[4].y);
    float2 t4 = make_float2(a[2].x - a[3].x, a[2].y - a[3].y);
    float2 u1 = make_float2(a0.x + C1*t1.x + C2*t2.x, a0.y + C1*t1.y + C2*t2.y);
    float2 u2 = make_float2(a0.x + C2*t1.x + C1*t2.x, a0.y + C2*t1.y + C1*t2.y);
    float2 v1 = make_float2(S1*t3.x + S2*t4.x, S1*t3.y + S2*t4.y);
    float2 v2 = make_float2(S2*t3.x - S1*t4.x, S2*t3.y - S1*t4.y);
    a[0] = make_float2(a0.x + t1.x + t2.x, a0.y + t1.y + t2.y);
    if (!inv) {
        a[1] = make_float2(u1.x + v1.y, u1.y - v1.x);
        a[4] = make_float2(u1.x - v1.y, u1.y + v1.x);
        a[2] = make_float2(u2.x + v2.y, u2.y - v2.x);
        a[3] = make_float2(u2.x - v2.y, u2.y + v2.x);
    } else {
        a[1] = make_float2(u1.x - v1.y, u1.y + v1.x);
        a[4] = make_float2(u1.x + v1.y, u1.y - v1.x);
        a[2] = make_float2(u2.x - v2.y, u2.y + v2.x);
        a[3] = make_float2(u2.x + v2.y, u2.y - v2.x);
    }
}

// ---------- branchless lane FFT-64 ----------
__device__ __forceinline__ void lane_fft_fwd(float2& v, const TwF& m) {
#pragma unroll
    for (int s = 0; s < 6; ++s) {
        int h = 32 >> s;
        float2 o = shflx(v, h);
        v.x = o.x + m.sgn[s] * v.x;
        v.y = o.y + m.sgn[s] * v.y;
        if (s < 5) v = cmul(v, m.f[s]);
    }
}
__device__ __forceinline__ void lane_fft_inv(float2& v, const TwI& m) {
#pragma unroll
    for (int s = 5; s >= 0; --s) {
        if (s < 5) v = cmul(v, m.i[s]);
        int h = 32 >> s;
        float2 o = shflx(v, h);
        v.x = o.x + m.sgn[s] * v.x;
        v.y = o.y + m.sgn[s] * v.y;
    }
}

// forward: a[k]=x[t+64k] natural -> a[j]=X[5*rev6(t)+j]
__device__ __forceinline__ void fft320_fwd(float2 a[5], const TwF& m) {
    radix5(a, false);
#pragma unroll
    for (int j = 1; j < 5; ++j) a[j] = cmul(a[j], m.w5[j - 1]);
#pragma unroll
    for (int j = 0; j < 5; ++j) lane_fft_fwd(a[j], m);
}
// inverse (unnormalized): a[j]=X[5*rev6(t)+j] -> a[k]=320*x[t+64k]
__device__ __forceinline__ void fft320_inv(float2 a[5], const TwI& m) {
#pragma unroll
    for (int j = 0; j < 5; ++j) lane_fft_inv(a[j], m);
#pragma unroll
    for (int j = 1; j < 5; ++j) a[j] = cmulc(a[j], m.w5[j - 1]);
    radix5(a, true);
}

// ---------- block reduction: wave shuffle + LDS + single atomic ----------
__device__ __forceinline__ void block_reduce_atomic(float d, float* dst) {
#pragma unroll
    for (int m = 32; m; m >>= 1) d += __shfl_xor(d, m, 64);
    __shared__ float ls[4];
    int lane = threadIdx.x & 63, wv = threadIdx.x >> 6;
    if (lane == 0) ls[wv] = d;
    __syncthreads();
    if (threadIdx.x == 0) atomicAdd(dst, ls[0] + ls[1] + ls[2] + ls[3]);
}

// ---------- kernels ----------
__global__ void k_zero_scal(float* scal) { scal[threadIdx.x] = 0.0f; }

// maskpT[b][pw][ph] = mask[b][f(ph)][f(pw)] / 102400   (f(p)=5*rev6(p/5)+p%5)
__global__ void k_maskp(const int* __restrict__ mask, float* __restrict__ maskpT) {
    int gid = blockIdx.x * 256 + threadIdx.x;
    int b = gid / HW; int rem = gid - b * HW;
    int pw = rem / WW; int ph = rem - pw * WW;
    int th = ph / 5, jh = ph - th * 5;
    int Kh = 5 * (int)(__brev((unsigned)th) >> 26) + jh;
    int tw_ = pw / 5, jw = pw - tw_ * 5;
    int Kw = 5 * (int)(__brev((unsigned)tw_) >> 26) + jw;
    float v = mask[(size_t)b * HW + Kh * WW + Kw] ? (1.0f / 102400.0f) : 0.0f;
    maskpT[gid] = v;
}

// x=0, r=p=rhs_c, rTr0 -> scal[b]. 400 blocks, 8 complex/thread, float4 I/O.
__global__ __launch_bounds__(256) void k_init(const float* __restrict__ rhs,
                                              float4* __restrict__ x4,
                                              float4* __restrict__ r4,
                                              float4* __restrict__ p4,
                                              float* __restrict__ scal) {
    int blk = blockIdx.x, tid = threadIdx.x;
    int b = blk / 50;
    size_t off = (size_t)blk * 2048 + (size_t)tid * 8;
    size_t hw = off - (size_t)b * HW;
    const float4* re4 = (const float4*)(rhs + (size_t)(2 * b) * HW + hw);
    const float4* im4 = (const float4*)(rhs + (size_t)(2 * b + 1) * HW + hw);
    float4 re0 = re4[0], re1 = re4[1];
    float4 im0 = im4[0], im1 = im4[1];
    float4 z = make_float4(0.f, 0.f, 0.f, 0.f);
    size_t o4 = off >> 1;
    x4[o4 + 0] = z; x4[o4 + 1] = z; x4[o4 + 2] = z; x4[o4 + 3] = z;
    float4 v0 = make_float4(re0.x, im0.x, re0.y, im0.y);
    float4 v1 = make_float4(re0.z, im0.z, re0.w, im0.w);
    float4 v2 = make_float4(re1.x, im1.x, re1.y, im1.y);
    float4 v3 = make_float4(re1.z, im1.z, re1.w, im1.w);
    r4[o4 + 0] = v0; r4[o4 + 1] = v1; r4[o4 + 2] = v2; r4[o4 + 3] = v3;
    p4[o4 + 0] = v0; p4[o4 + 1] = v1; p4[o4 + 2] = v2; p4[o4 + 3] = v3;
    float d = re0.x*re0.x + re0.y*re0.y + re0.z*re0.z + re0.w*re0.w
            + re1.x*re1.x + re1.y*re1.y + re1.z*re1.z + re1.w*re1.w
            + im0.x*im0.x + im0.y*im0.y + im0.z*im0.z + im0.w*im0.w
            + im1.x*im1.x + im1.y*im1.y + im1.z*im1.z + im1.w*im1.w;
    block_reduce_atomic(d, &scal[b]);
}

// A: coil = csm*p, FFT along w, store digit-permuted rows
__global__ __launch_bounds__(256) void k_rowfft(const float* __restrict__ csm,
                                                const float2* __restrict__ p,
                                                float2* __restrict__ kbuf, int b0) {
    int row = blockIdx.x * 4 + (threadIdx.x >> 6);
    int t = threadIdx.x & 63;
    int h = row % HH; int bc = row / HH;
    int c = bc & 15; int bl = bc >> 4; int b = b0 + bl;
    TwF m; make_twf(t, m);
    const float2* csm2 = (const float2*)csm;
    size_t pbase = (size_t)b * HW + (size_t)h * WW;
    size_t cbase = ((size_t)(b * NC + c) * HH + h) * WW;
    float2 a[5];
#pragma unroll
    for (int k = 0; k < 5; ++k) {
        float2 pv = p[pbase + t + 64 * k];
        float2 cv = csm2[cbase + t + 64 * k];
        a[k] = cmul(cv, pv);
    }
    fft320_fwd(a, m);
    size_t ob = ((size_t)bc * HH + h) * WW + 5 * t;
#pragma unroll
    for (int j = 0; j < 5; ++j) kbuf[ob + j] = a[j];
}

// B: per 320x8 column tile: FFT over h, mask, IFFT over h (in place)
// LDS: split re/im, 17-float row stride (odd) -> conflict-free FFT reads.
__global__ __launch_bounds__(256) void k_colpass(float2* __restrict__ kbuf,
                                                 const float* __restrict__ maskpT, int b0) {
    int tile = blockIdx.x;
    int w0 = (tile % 40) * 8; int bc = tile / 40;
    int b = b0 + (bc >> 4);
    __shared__ float lds[HH * 17];
    size_t kbase = (size_t)bc * HW;
    for (int i = threadIdx.x; i < HH * 8; i += 256) {
        int hh = i >> 3, wc = i & 7;
        float2 v = kbuf[kbase + (size_t)hh * WW + w0 + wc];
        lds[hh * 17 + wc] = v.x;
        lds[hh * 17 + 8 + wc] = v.y;
    }
    __syncthreads();
    int t = threadIdx.x & 63; int wv = threadIdx.x >> 6;
    TwF mf; make_twf(t, mf);
    TwI mi; make_twi(t, mi);
#pragma unroll
    for (int wc = 0; wc < 2; ++wc) {
        int w = wv * 2 + wc;
        float2 a[5];
#pragma unroll
        for (int k = 0; k < 5; ++k) {
            int base = (t + 64 * k) * 17;
            a[k] = make_float2(lds[base + w], lds[base + 8 + w]);
        }
        fft320_fwd(a, mf);
        const float* mp = maskpT + ((size_t)b * WW + (w0 + w)) * HH + 5 * t;
#pragma unroll
        for (int j = 0; j < 5; ++j) { float mm = mp[j]; a[j].x *= mm; a[j].y *= mm; }
        fft320_inv(a, mi);
#pragma unroll
        for (int k = 0; k < 5; ++k) {
            int base = (t + 64 * k) * 17;
            lds[base + w] = a[k].x;
            lds[base + 8 + w] = a[k].y;
        }
    }
    __syncthreads();
    for (int i = threadIdx.x; i < HH * 8; i += 256) {
        int hh = i >> 3, wc = i & 7;
        float2 v = make_float2(lds[hh * 17 + wc], lds[hh * 17 + 8 + wc]);
        kbuf[kbase + (size_t)hh * WW + w0 + wc] = v;
    }
}

// C: IFFT along w, combine conj(csm)*img over coils, Ap = . + lam*p, pAp.
// 256 threads/block: wave wv handles coils 4wv..4wv+3; LDS cross-wave reduce.
__global__ __launch_bounds__(256) void k_combine(const float* __restrict__ csm,
                                                 const float2* __restrict__ kbuf,
                                                 const float2* __restrict__ p,
                                                 float2* __restrict__ Ap,
                                                 const float* __restrict__ lam,
                                                 float* __restrict__ scal, int b0, int it) {
    int t = threadIdx.x & 63, wv = threadIdx.x >> 6;
    int h = blockIdx.x % HH; int bl = blockIdx.x / HH; int b = b0 + bl;
    TwI m; make_twi(t, m);
    const float2* csm2 = (const float2*)csm;
    float2 acc[5];
#pragma unroll
    for (int k = 0; k < 5; ++k) acc[k] = make_float2(0.f, 0.f);
#pragma unroll
    for (int cc = 0; cc < 4; ++cc) {
        int c = wv * 4 + cc;
        size_t kb = ((size_t)(bl * NC + c) * HH + h) * WW + 5 * t;
        float2 a[5];
#pragma unroll
        for (int j = 0; j < 5; ++j) a[j] = kbuf[kb + j];
        fft320_inv(a, m);
        size_t cb = ((size_t)(b * NC + c) * HH + h) * WW;
#pragma unroll
        for (int k = 0; k < 5; ++k) {
            float2 cv = csm2[cb + t + 64 * k];
            float2 mm = cmulc(a[k], cv);
            acc[k].x += mm.x; acc[k].y += mm.y;
        }
    }
    __shared__ float2 red[3][64][5];
    if (wv > 0) {
#pragma unroll
        for (int k = 0; k < 5; ++k) red[wv - 1][t][k] = acc[k];
    }
    __syncthreads();
    if (wv == 0) {
#pragma unroll
        for (int k = 0; k < 5; ++k) {
            acc[k].x += red[0][t][k].x + red[1][t][k].x + red[2][t][k].x;
            acc[k].y += red[0][t][k].y + red[1][t][k].y + red[2][t][k].y;
        }
        float lamv = lam[0];
        size_t pb = (size_t)b * HW + (size_t)h * WW;
        float dot = 0.f;
#pragma unroll
        for (int k = 0; k < 5; ++k) {
            float2 pv = p[pb + t + 64 * k];
            float2 apv = make_float2(acc[k].x + lamv * pv.x, acc[k].y + lamv * pv.y);
            Ap[pb + t + 64 * k] = apv;
            dot += pv.x * apv.x + pv.y * apv.y;
        }
#pragma unroll
        for (int mk = 32; mk; mk >>= 1) dot += __shfl_xor(dot, mk, 64);
        if (t == 0) atomicAdd(&scal[8 + it * 8 + b], dot);
    }
}

// U1: x += a p; r -= a Ap; rTr_new reduction. 400 blocks, 8 complex/thread.
__global__ __launch_bounds__(256) void k_update1(float4* __restrict__ x,
                                                 float4* __restrict__ r,
                                                 const float4* __restrict__ p,
                                                 const float4* __restrict__ Ap,
                                                 float* __restrict__ scal, int it) {
    if (((const int*)scal)[168] != 0) return;
    int blk = blockIdx.x, tid = threadIdx.x;
    int b = blk / 50;
    float alpha = scal[b] / scal[8 + it * 8 + b];
    size_t o4 = (size_t)blk * 1024 + (size_t)tid * 4;
    float d = 0.f;
#pragma unroll
    for (int j = 0; j < 4; ++j) {
        float4 pv = p[o4 + j], av = Ap[o4 + j];
        float4 xv = x[o4 + j], rv = r[o4 + j];
        xv.x += alpha * pv.x; xv.y += alpha * pv.y;
        xv.z += alpha * pv.z; xv.w += alpha * pv.w;
        rv.x -= alpha * av.x; rv.y -= alpha * av.y;
        rv.z -= alpha * av.z; rv.w -= alpha * av.w;
        x[o4 + j] = xv; r[o4 + j] = rv;
        d += rv.x*rv.x + rv.y*rv.y + rv.z*rv.z + rv.w*rv.w;
    }
    block_reduce_atomic(d, &scal[88 + it * 8 + b]);
}

// U2: p = r + beta p. 400 blocks, 8 complex/thread.
__global__ __launch_bounds__(256) void k_update2(const float4* __restrict__ r,
                                                 float4* __restrict__ p,
                                                 const float* __restrict__ scal, int it) {
    if (((const int*)scal)[168] != 0) return;
    int blk = blockIdx.x, tid = threadIdx.x;
    int b = blk / 50;
    float beta = scal[88 + it * 8 + b] / scal[b];
    size_t o4 = (size_t)blk * 1024 + (size_t)tid * 4;
#pragma unroll
    for (int j = 0; j < 4; ++j) {
        float4 rv = r[o4 + j], pv = p[o4 + j];
        pv.x = rv.x + beta * pv.x; pv.y = rv.y + beta * pv.y;
        pv.z = rv.z + beta * pv.z; pv.w = rv.w + beta * pv.w;
        p[o4 + j] = pv;
    }
}

// U3: rTrc <- rTr_new; done |= max(rTr_new) < EPS
__global__ void k_update3(float* __restrict__ scal, int it) {
    int t = threadIdx.x;
    int* dn = (int*)scal + 168;
    if (*dn) return;
    float v = (t < 8) ? scal[88 + it * 8 + t] : 0.0f;
    if (t < 8) scal[t] = v;
    float m = v;
#pragma unroll
    for (int mk = 32; mk; mk >>= 1) m = fmaxf(m, __shfl_xor(m, mk, 64));
    if (t == 0 && m < CGEPS) *dn = 1;
}

extern "C" void kernel_launch(void* const* d_in, const int* in_sizes, int n_in,
                              void* d_out, int out_size, void* d_ws, size_t ws_size,
                              hipStream_t stream) {
    const float* rhs = (const float*)d_in[0];
    const float* csm = (const float*)d_in[1];
    const int* mask = (const int*)d_in[2];
    const float* lam = (const float*)d_in[3];

    char* w = (char*)d_ws;
    float2* x = (float2*)w;        w += (size_t)NB * HW * sizeof(float2);
    float2* r = (float2*)w;        w += (size_t)NB * HW * sizeof(float2);
    float2* p = (float2*)w;        w += (size_t)NB * HW * sizeof(float2);
    float2* Ap = (float2*)w;       w += (size_t)NB * HW * sizeof(float2);
    float* maskpT = (float*)w;     w += (size_t)NB * HW * sizeof(float);
    float* scal = (float*)w;       w += 4096;
    float2* kbuf = (float2*)w;

    size_t used = (size_t)(w - (char*)d_ws);
    size_t per_b = (size_t)NC * HW * sizeof(float2);
    int CB = 1;
    if (ws_size > used) {
        size_t avail = ws_size - used;
        CB = (int)(avail / per_b);
        if (CB > NB) CB = NB;
        if (CB < 1) CB = 1;
    }

    k_zero_scal<<<1, 256, 0, stream>>>(scal);
    k_maskp<<<(NB * HW) / 256, 256, 0, stream>>>(mask, maskpT);
    k_init<<<400, 256, 0, stream>>>(rhs, (float4*)x, (float4*)r, (float4*)p, scal);

    for (int it = 0; it < NITER; ++it) {
        for (int b0 = 0; b0 < NB; b0 += CB) {
            int nb = (NB - b0 < CB) ? (NB - b0) : CB;
            k_rowfft<<<nb * NC * HH / 4, 256, 0, stream>>>(csm, p, kbuf, b0);
            k_colpass<<<nb * NC * 40, 256, 0, stream>>>(kbuf, maskpT, b0);
            k_combine<<<nb * HH, 256, 0, stream>>>(csm, kbuf, p, Ap, lam, scal, b0, it);
        }
        k_update1<<<400, 256, 0, stream>>>((float4*)x, (float4*)r, (const float4*)p,
                                           (const float4*)Ap, scal, it);
        k_update2<<<400, 256, 0, stream>>>((const float4*)r, (float4*)p, scal, it);
        k_update3<<<1, 64, 0, stream>>>(scal, it);
    }
    hipMemcpyAsync(d_out, x, (size_t)NB * HW * sizeof(float2),
                   hipMemcpyDeviceToDevice, stream);
}